// Round 3
// baseline (195.247 us; speedup 1.0000x reference)
//
#include <hip/hip_runtime.h>
#include <hip/hip_fp16.h>
#include <math.h>

#define N_NODES 10000
#define N_EDGES 160000
#define B_ 8
#define D_ 64
#define BD 512          // B_*D_
#define ROWS 80000      // N_NODES*B_

typedef _Float16 f16x8 __attribute__((ext_vector_type(8)));
typedef float f32x4 __attribute__((ext_vector_type(4)));

// ---------------- prep: zero counts + build transposed fp16 weight ----------------
// blocks 0..39: zero counts (40*256=10240 >= 10000)
// blocks 40..71: Wt[c*64+k] = (fp16) weight[((c>>6)*64 + k)*64 + (c&63)], c in [0,128), k in [0,64)
__global__ void zero_wt_kernel(int* __restrict__ counts,
                               const float* __restrict__ weight,
                               _Float16* __restrict__ Wt) {
    int bid = blockIdx.x;
    int t = threadIdx.x;
    if (bid < 40) {
        int i = bid * 256 + t;
        if (i < N_NODES) counts[i] = 0;
    } else {
        int i = (bid - 40) * 256 + t;   // 0..8191
        int c = i >> 6, k = i & 63;
        Wt[i] = (_Float16)weight[(((c >> 6) * 64 + k) << 6) + (c & 63)];
    }
}

__global__ void hist_kernel(const int* __restrict__ dst, int* __restrict__ counts) {
    int e = blockIdx.x * blockDim.x + threadIdx.x;
    if (e < N_EDGES) atomicAdd(&counts[dst[e]], 1);
}

// single block, 256 threads; counts staged through LDS
__global__ void scan_kernel(const int* __restrict__ counts,
                            int* __restrict__ offsets, int* __restrict__ cursor) {
    __shared__ int c_lds[10240];
    __shared__ int sums[256];
    int t = threadIdx.x;
    for (int i = t; i < 10240; i += 256) c_lds[i] = (i < N_NODES) ? counts[i] : 0;
    __syncthreads();
    int base = t * 40;
    int local[40];
    int s = 0;
#pragma unroll
    for (int i = 0; i < 40; i++) {
        local[i] = s;
        s += c_lds[base + i];
    }
    sums[t] = s;
    __syncthreads();
    for (int off = 1; off < 256; off <<= 1) {
        int v = (t >= off) ? sums[t - off] : 0;
        __syncthreads();
        sums[t] += v;
        __syncthreads();
    }
    int ex = (t == 0) ? 0 : sums[t - 1];
#pragma unroll
    for (int i = 0; i < 40; i++) {
        int idx = base + i;
        if (idx < N_NODES) {
            int o = ex + local[i];
            offsets[idx] = o;
            cursor[idx] = o;
        }
    }
    if (t == 255) offsets[N_NODES] = sums[255];
}

__global__ void scatter_kernel(const int* __restrict__ src, const int* __restrict__ dst,
                               const float* __restrict__ dist,
                               int* __restrict__ cursor, int2* __restrict__ edges) {
    int e = blockIdx.x * blockDim.x + threadIdx.x;
    if (e < N_EDGES) {
        int d = dst[e];
        int pos = atomicAdd(&cursor[d], 1);
        edges[pos] = make_int2(src[e], __float_as_int(dist[e]));
    }
}

// ---------------- MFMA node projection ----------------
// P[m][c] = sum_k state[m][k] * Wt[c][k]  (c<64 -> p_src, c>=64 -> p_dst)
// Wave computes a 16(M) x 128(C) strip via 8 col-tiles x 2 k-halves of
// v_mfma_f32_16x16x32_f16. No LDS; fragments straight from global.
//   A-frag: lane holds A[m=lane&15][k=quad*8+j]
//   B-frag: lane holds B[k=quad*8+j][n=lane&15]  (from Wt[n][k], k-contiguous)
//   D-frag: reg r holds D[m=quad*4+r][n=lane&15]
__global__ void __launch_bounds__(256) proj_mfma(const float* __restrict__ state,
                                                 const _Float16* __restrict__ Wt,
                                                 __half2* __restrict__ G,
                                                 __half* __restrict__ Pd) {
    int tid = threadIdx.x;
    int wave = tid >> 6, lane = tid & 63;
    int quad = lane >> 4, m16 = lane & 15;
    int m_base = blockIdx.x * 64 + wave * 16;

    const float4* arow = (const float4*)(state + (size_t)(m_base + m16) * 64);
    float4 a00 = arow[quad * 2];
    float4 a01 = arow[quad * 2 + 1];      // k = quad*8 .. +7
    float4 a10 = arow[8 + quad * 2];
    float4 a11 = arow[9 + quad * 2];      // k = 32 + quad*8 .. +7

    f16x8 af0, af1;
    af0[0] = (_Float16)a00.x; af0[1] = (_Float16)a00.y; af0[2] = (_Float16)a00.z; af0[3] = (_Float16)a00.w;
    af0[4] = (_Float16)a01.x; af0[5] = (_Float16)a01.y; af0[6] = (_Float16)a01.z; af0[7] = (_Float16)a01.w;
    af1[0] = (_Float16)a10.x; af1[1] = (_Float16)a10.y; af1[2] = (_Float16)a10.z; af1[3] = (_Float16)a10.w;
    af1[4] = (_Float16)a11.x; af1[5] = (_Float16)a11.y; af1[6] = (_Float16)a11.z; af1[7] = (_Float16)a11.w;

#pragma unroll
    for (int tcol = 0; tcol < 8; tcol++) {
        const _Float16* wrow = Wt + (((tcol * 16 + m16) << 6) + quad * 8);
        f16x8 b0 = *(const f16x8*)(wrow);
        f16x8 b1 = *(const f16x8*)(wrow + 32);
        f32x4 acc = {0.f, 0.f, 0.f, 0.f};
        acc = __builtin_amdgcn_mfma_f32_16x16x32_f16(af0, b0, acc, 0, 0, 0);
        acc = __builtin_amdgcn_mfma_f32_16x16x32_f16(af1, b1, acc, 0, 0, 0);
        int n = tcol * 16 + m16;
#pragma unroll
        for (int r = 0; r < 4; r++) {
            int m = m_base + quad * 4 + r;
            float p = acc[r];
            if (tcol < 4) {
                float x = state[m * 64 + n];
                G[m * 64 + n] = __floats2half2_rn(p, x);   // low = p_src, high = state
            } else {
                Pd[m * 64 + (n - 64)] = __float2half_rn(p);
            }
        }
    }
}

// ---------------- fused segment-softmax + aggregate ----------------
// One wave per (node, batch-slice). slice index = blockIdx & 7 so that with
// round-robin block->XCD dispatch each XCD gathers only a 2.56 MB slice of G
// (fits its 4 MiB L2). alpha bounded => plain exp (no online max).
__global__ void __launch_bounds__(64) gat_aggregate(
    const __half2* __restrict__ G,
    const __half* __restrict__ Pd,
    const int* __restrict__ offsets,
    const int2* __restrict__ edges,
    float* __restrict__ out) {
    int bid = blockIdx.x;
    int b = bid & 7;            // batch slice -> XCD
    int n = bid >> 3;           // dst node
    int t = threadIdx.x;        // d = t
    int e = (b << 6) + t;       // element index within node, 0..511

    size_t dbase = (size_t)n * BD + e;
    float pd = __half2float(Pd[dbase]);
    int off = offsets[n];
    int end = offsets[n + 1];
    float l = 0.f, o = 0.f;

    int j = off;
    if (j < end) {
        int2 rec = edges[j];
        int s = rec.x;
        float dd = __int_as_float(rec.y);
        __half2 g = G[(size_t)s * BD + e];
        for (;;) {
            int jn = j + 1;
            bool more = jn < end;
            int s2 = s; float dd2 = dd; __half2 g2 = g;
            if (more) {
                int2 rec2 = edges[jn];
                s2 = rec2.x;
                dd2 = __int_as_float(rec2.y);
                g2 = G[(size_t)s2 * BD + e];
            }
            float p = __low2float(g);
            float x = __high2float(g);
            float z = p + pd;
            float a = (z > 0.f ? z : 0.2f * z) * dd;
            float ex = __expf(a);
            l += ex;
            o = fmaf(ex, x, o);
            if (!more) break;
            j = jn; s = s2; dd = dd2; g = g2;
        }
    }
    out[dbase] = (end > off) ? fmaxf(o / l, 0.f) : 0.f;
}

extern "C" void kernel_launch(void* const* d_in, const int* in_sizes, int n_in,
                              void* d_out, int out_size, void* d_ws, size_t ws_size,
                              hipStream_t stream) {
    const float* state  = (const float*)d_in[0];
    // d_in[1] = feature (unused by the math)
    const float* weight = (const float*)d_in[2];
    const int*   src    = (const int*)d_in[3];
    const int*   dst    = (const int*)d_in[4];
    const float* dist   = (const float*)d_in[5];

    // workspace layout (16B-aligned head first)
    __half2*  G      = (__half2*)d_ws;                       // ROWS*64 half2 = 20.48 MB
    __half*   Pd     = (__half*)(G + (size_t)ROWS * 64);     // ROWS*64 half  = 10.24 MB
    _Float16* Wt     = (_Float16*)(Pd + (size_t)ROWS * 64);  // 8192 half = 16 KB
    int2*     edges  = (int2*)(Wt + 8192);                   // E int2 = 1.28 MB
    int*      counts = (int*)(edges + N_EDGES);              // N
    int*      offsets= counts + N_NODES;                     // N+1
    int*      cursor = offsets + N_NODES + 1;                // N

    zero_wt_kernel<<<72, 256, 0, stream>>>(counts, weight, Wt);
    hist_kernel<<<(N_EDGES + 255) / 256, 256, 0, stream>>>(dst, counts);
    scan_kernel<<<1, 256, 0, stream>>>(counts, offsets, cursor);
    scatter_kernel<<<(N_EDGES + 255) / 256, 256, 0, stream>>>(src, dst, dist, cursor, edges);
    proj_mfma<<<ROWS / 64, 256, 0, stream>>>(state, Wt, G, Pd);
    gat_aggregate<<<N_NODES * 8, 64, 0, stream>>>(G, Pd, offsets, edges, (float*)d_out);
}

// Round 4
// 192.264 us; speedup vs baseline: 1.0155x; 1.0155x over previous
//
#include <hip/hip_runtime.h>
#include <hip/hip_fp16.h>
#include <math.h>

#define N_NODES 10000
#define N_EDGES 160000
#define B_ 8
#define D_ 64
#define BD 512          // B_*D_
#define ROWS 80000      // N_NODES*B_

typedef _Float16 f16x8 __attribute__((ext_vector_type(8)));
typedef float f32x4 __attribute__((ext_vector_type(4)));

union HU { _Float16 f; unsigned short u; };

// ---------------- prep: zero counts + build transposed fp16 weight ----------------
// blocks 0..39: zero counts. blocks 40..71: Wt[c*64+k] = fp16 weight[((c>>6)*64+k)*64 + (c&63)]
__global__ void zero_wt_kernel(int* __restrict__ counts,
                               const float* __restrict__ weight,
                               _Float16* __restrict__ Wt) {
    int bid = blockIdx.x;
    int t = threadIdx.x;
    if (bid < 40) {
        int i = bid * 256 + t;
        if (i < N_NODES) counts[i] = 0;
    } else {
        int i = (bid - 40) * 256 + t;   // 0..8191
        int c = i >> 6, k = i & 63;
        Wt[i] = (_Float16)weight[(((c >> 6) * 64 + k) << 6) + (c & 63)];
    }
}

__global__ void hist_kernel(const int* __restrict__ dst, int* __restrict__ counts) {
    int e = blockIdx.x * blockDim.x + threadIdx.x;
    if (e < N_EDGES) atomicAdd(&counts[dst[e]], 1);
}

// single block, 1024 threads; counts staged through LDS
__global__ void __launch_bounds__(1024) scan_kernel(const int* __restrict__ counts,
                                                    int* __restrict__ offsets,
                                                    int* __restrict__ cursor) {
    __shared__ int c_lds[10240];
    __shared__ int sums[1024];
    int t = threadIdx.x;
    for (int i = t; i < 10240; i += 1024) c_lds[i] = (i < N_NODES) ? counts[i] : 0;
    __syncthreads();
    int base = t * 10;
    int local[10];
    int s = 0;
#pragma unroll
    for (int i = 0; i < 10; i++) {
        local[i] = s;
        s += c_lds[base + i];
    }
    sums[t] = s;
    __syncthreads();
    for (int off = 1; off < 1024; off <<= 1) {
        int v = (t >= off) ? sums[t - off] : 0;
        __syncthreads();
        sums[t] += v;
        __syncthreads();
    }
    int ex = (t == 0) ? 0 : sums[t - 1];
#pragma unroll
    for (int i = 0; i < 10; i++) {
        int idx = base + i;
        if (idx < N_NODES) {
            int o = ex + local[i];
            offsets[idx] = o;
            cursor[idx] = o;
        }
    }
    if (t == 1023) offsets[N_NODES] = sums[1023];
}

__global__ void scatter_kernel(const int* __restrict__ src, const int* __restrict__ dst,
                               const float* __restrict__ dist,
                               int* __restrict__ cursor, int2* __restrict__ edges) {
    int e = blockIdx.x * blockDim.x + threadIdx.x;
    if (e < N_EDGES) {
        int d = dst[e];
        int pos = atomicAdd(&cursor[d], 1);
        edges[pos] = make_int2(src[e], __float_as_int(dist[e]));
    }
}

// ---------------- MFMA node projection, LDS-staged fragments ----------------
// P[m][c] = sum_k state[m][k] * Wt[c][k].  Block: 256 thr / 4 waves / 64 rows.
// LDS tiles padded to 72 halves/row (144 B: 16B-aligned, 2-way bank aliasing only).
//   A-frag: lane holds A[m=lane&15][k=quad*8+j]     (ds_read_b128)
//   B-frag: lane holds B[k=quad*8+j][n=lane&15]     (from Wt[n][k], k-contiguous)
//   D-frag: reg r holds D[m=quad*4+r][n=lane&15]
__global__ void __launch_bounds__(256) proj_mfma(const float* __restrict__ state,
                                                 const _Float16* __restrict__ Wt,
                                                 __half2* __restrict__ G,
                                                 __half* __restrict__ Pd) {
    __shared__ _Float16 At[64 * 72];    // 18 KB
    __shared__ _Float16 Bt[128 * 72];   // 18 KB
    int tid = threadIdx.x;
    int row0 = blockIdx.x * 64;

    // stage state tile (coalesced float4) -> fp16 LDS
    const float4* st4 = (const float4*)(state + (size_t)row0 * 64);
    for (int i = tid; i < 1024; i += 256) {
        int r = i >> 4, c4 = (i & 15) << 2;
        float4 v = st4[i];
        union { short4 s; _Float16 h[4]; } u;
        u.h[0] = (_Float16)v.x; u.h[1] = (_Float16)v.y;
        u.h[2] = (_Float16)v.z; u.h[3] = (_Float16)v.w;
        *(short4*)&At[r * 72 + c4] = u.s;
    }
    // stage Wt (already fp16, 16 KB) -> LDS
    const short4* wt4 = (const short4*)Wt;
    for (int i = tid; i < 2048; i += 256) {
        int r = i >> 4, c4 = (i & 15) << 2;
        *(short4*)&Bt[r * 72 + c4] = wt4[i];
    }
    __syncthreads();

    int wave = tid >> 6, lane = tid & 63;
    int quad = lane >> 4, m16 = lane & 15;
    int m_loc = wave * 16 + m16;

    f16x8 a0 = *(const f16x8*)&At[m_loc * 72 + quad * 8];        // k = quad*8..+7
    f16x8 a1 = *(const f16x8*)&At[m_loc * 72 + 32 + quad * 8];   // k = 32+quad*8..+7

#pragma unroll
    for (int tcol = 0; tcol < 8; tcol++) {
        int n = tcol * 16 + m16;
        f16x8 b0 = *(const f16x8*)&Bt[n * 72 + quad * 8];
        f16x8 b1 = *(const f16x8*)&Bt[n * 72 + 32 + quad * 8];
        f32x4 acc = {0.f, 0.f, 0.f, 0.f};
        acc = __builtin_amdgcn_mfma_f32_16x16x32_f16(a0, b0, acc, 0, 0, 0);
        acc = __builtin_amdgcn_mfma_f32_16x16x32_f16(a1, b1, acc, 0, 0, 0);
#pragma unroll
        for (int r = 0; r < 4; r++) {
            int ml = wave * 16 + quad * 4 + r;
            size_t m = row0 + ml;
            if (tcol < 4) {
                HU xu; xu.f = At[ml * 72 + n];
                ushort2 pk;
                pk.x = __half_as_ushort(__float2half_rn(acc[r]));
                pk.y = xu.u;
                *(ushort2*)&G[m * 64 + n] = pk;     // low = p_src, high = state(fp16)
            } else {
                Pd[m * 64 + (n - 64)] = __float2half_rn(acc[r]);
            }
        }
    }
}

// ---------------- fused segment-softmax + aggregate ----------------
// 4 waves/block; wave w handles node grp*4+w, slice b = blockIdx&7 (XCD-resident
// 2.56 MB G slice per XCD). 4-deep chunked software pipeline over edges.
// alpha bounded => plain exp2; leaky_relu(z) == max(z, 0.2z); log2e folded into dist.
__global__ void __launch_bounds__(256) gat_aggregate(
    const __half2* __restrict__ G,
    const __half* __restrict__ Pd,
    const int* __restrict__ offsets,
    const int2* __restrict__ edges,
    float* __restrict__ out) {
    int bid = blockIdx.x;
    int b = bid & 7;            // batch slice -> XCD
    int grp = bid >> 3;
    int wave = threadIdx.x >> 6;
    int lane = threadIdx.x & 63;
    int n = grp * 4 + wave;     // dst node
    int e = (b << 6) + lane;    // element index within node, 0..511

    size_t dbase = (size_t)n * BD + e;
    float pd = __half2float(Pd[dbase]);
    int off = offsets[n];
    int cnt = offsets[n + 1] - off;
    const int2* ep = edges + off;
    const float LOG2E = 1.44269504f;

    float l = 0.f, o = 0.f;

    __half2 gbuf[4];
    float dl[4];
    int head = cnt < 4 ? cnt : 4;
#pragma unroll
    for (int i = 0; i < 4; i++) {
        if (i < head) {
            int2 r = ep[i];
            dl[i] = __int_as_float(r.y) * LOG2E;
            gbuf[i] = G[(size_t)r.x * BD + e];
        }
    }

    int j = 0;
    while (j + 4 <= cnt) {
        __half2 g2[4];
        float dl2[4];
        int rem = cnt - (j + 4);
        int nl = rem < 4 ? rem : 4;
#pragma unroll
        for (int i = 0; i < 4; i++) {
            if (i < nl) {
                int2 r = ep[j + 4 + i];
                dl2[i] = __int_as_float(r.y) * LOG2E;
                g2[i] = G[(size_t)r.x * BD + e];
            }
        }
#pragma unroll
        for (int i = 0; i < 4; i++) {
            float p = __low2float(gbuf[i]);
            float x = __high2float(gbuf[i]);
            float z = p + pd;
            float a = fmaxf(z, 0.2f * z) * dl[i];
            float ex = __builtin_amdgcn_exp2f(a);
            l += ex;
            o = fmaf(ex, x, o);
        }
#pragma unroll
        for (int i = 0; i < 4; i++) { gbuf[i] = g2[i]; dl[i] = dl2[i]; }
        j += 4;
    }
    int tl = cnt - j;   // 0..3 edges already resident in gbuf
#pragma unroll
    for (int i = 0; i < 4; i++) {
        if (i < tl) {
            float p = __low2float(gbuf[i]);
            float x = __high2float(gbuf[i]);
            float z = p + pd;
            float a = fmaxf(z, 0.2f * z) * dl[i];
            float ex = __builtin_amdgcn_exp2f(a);
            l += ex;
            o = fmaf(ex, x, o);
        }
    }
    out[dbase] = (cnt > 0) ? fmaxf(o / l, 0.f) : 0.f;
}

extern "C" void kernel_launch(void* const* d_in, const int* in_sizes, int n_in,
                              void* d_out, int out_size, void* d_ws, size_t ws_size,
                              hipStream_t stream) {
    const float* state  = (const float*)d_in[0];
    // d_in[1] = feature (unused by the math)
    const float* weight = (const float*)d_in[2];
    const int*   src    = (const int*)d_in[3];
    const int*   dst    = (const int*)d_in[4];
    const float* dist   = (const float*)d_in[5];

    // workspace layout (16B-aligned head first)
    __half2*  G      = (__half2*)d_ws;                       // ROWS*64 half2 = 20.48 MB
    __half*   Pd     = (__half*)(G + (size_t)ROWS * 64);     // ROWS*64 half  = 10.24 MB
    _Float16* Wt     = (_Float16*)(Pd + (size_t)ROWS * 64);  // 8192 half = 16 KB
    int2*     edges  = (int2*)(Wt + 8192);                   // E int2 = 1.28 MB
    int*      counts = (int*)(edges + N_EDGES);              // N
    int*      offsets= counts + N_NODES;                     // N+1
    int*      cursor = offsets + N_NODES + 1;                // N

    zero_wt_kernel<<<72, 256, 0, stream>>>(counts, weight, Wt);
    hist_kernel<<<(N_EDGES + 255) / 256, 256, 0, stream>>>(dst, counts);
    scan_kernel<<<1, 1024, 0, stream>>>(counts, offsets, cursor);
    scatter_kernel<<<(N_EDGES + 255) / 256, 256, 0, stream>>>(src, dst, dist, cursor, edges);
    proj_mfma<<<ROWS / 64, 256, 0, stream>>>(state, Wt, G, Pd);
    gat_aggregate<<<N_NODES * 2, 256, 0, stream>>>(G, Pd, offsets, edges, (float*)d_out);
}

// Round 5
// 171.329 us; speedup vs baseline: 1.1396x; 1.1222x over previous
//
#include <hip/hip_runtime.h>
#include <hip/hip_fp16.h>
#include <math.h>

#define N_NODES 10000
#define N_EDGES 160000
#define B_ 8
#define D_ 64
#define BD 512          // B_*D_
#define ROWS 80000      // N_NODES*B_
#define SLICE 640000    // N_NODES*64 elements per batch-slice

typedef _Float16 f16x8 __attribute__((ext_vector_type(8)));
typedef float f32x4 __attribute__((ext_vector_type(4)));

union HU { _Float16 f; unsigned short u; };

// ---------------- prep: zero counts + build transposed fp16 weight ----------------
// blocks 0..39: zero counts. blocks 40..71: Wt[c*64+k] = fp16 weight[((c>>6)*64+k)*64 + (c&63)]
__global__ void zero_wt_kernel(int* __restrict__ counts,
                               const float* __restrict__ weight,
                               _Float16* __restrict__ Wt) {
    int bid = blockIdx.x;
    int t = threadIdx.x;
    if (bid < 40) {
        int i = bid * 256 + t;
        if (i < N_NODES) counts[i] = 0;
    } else {
        int i = (bid - 40) * 256 + t;   // 0..8191
        int c = i >> 6, k = i & 63;
        Wt[i] = (_Float16)weight[(((c >> 6) * 64 + k) << 6) + (c & 63)];
    }
}

__global__ void hist_kernel(const int* __restrict__ dst, int* __restrict__ counts) {
    int e = blockIdx.x * blockDim.x + threadIdx.x;
    if (e < N_EDGES) atomicAdd(&counts[dst[e]], 1);
}

// single block, 1024 threads; counts staged through LDS
__global__ void __launch_bounds__(1024) scan_kernel(const int* __restrict__ counts,
                                                    int* __restrict__ offsets,
                                                    int* __restrict__ cursor) {
    __shared__ int c_lds[10240];
    __shared__ int sums[1024];
    int t = threadIdx.x;
    for (int i = t; i < 10240; i += 1024) c_lds[i] = (i < N_NODES) ? counts[i] : 0;
    __syncthreads();
    int base = t * 10;
    int local[10];
    int s = 0;
#pragma unroll
    for (int i = 0; i < 10; i++) {
        local[i] = s;
        s += c_lds[base + i];
    }
    sums[t] = s;
    __syncthreads();
    for (int off = 1; off < 1024; off <<= 1) {
        int v = (t >= off) ? sums[t - off] : 0;
        __syncthreads();
        sums[t] += v;
        __syncthreads();
    }
    int ex = (t == 0) ? 0 : sums[t - 1];
#pragma unroll
    for (int i = 0; i < 10; i++) {
        int idx = base + i;
        if (idx < N_NODES) {
            int o = ex + local[i];
            offsets[idx] = o;
            cursor[idx] = o;
        }
    }
    if (t == 1023) offsets[N_NODES] = sums[1023];
}

__global__ void scatter_kernel(const int* __restrict__ src, const int* __restrict__ dst,
                               const float* __restrict__ dist,
                               int* __restrict__ cursor, int2* __restrict__ edges) {
    int e = blockIdx.x * blockDim.x + threadIdx.x;
    if (e < N_EDGES) {
        int d = dst[e];
        int pos = atomicAdd(&cursor[d], 1);
        edges[pos] = make_int2(src[e], __float_as_int(dist[e]));
    }
}

// ---------------- MFMA node projection, LDS-staged fragments ----------------
// P[m][c] = sum_k state[m][k] * Wt[c][k].  Block: 256 thr / 4 waves / 64 rows.
// Epilogue writes slice-major: row m = node*8+b maps to slice b=m&7, node=m>>3.
//   G[b*SLICE + node*64 + d]  = half2{p_src, state}
//   Pd[b*SLICE + node*64 + d] = half(p_dst)
__global__ void __launch_bounds__(256) proj_mfma(const float* __restrict__ state,
                                                 const _Float16* __restrict__ Wt,
                                                 __half2* __restrict__ G,
                                                 __half* __restrict__ Pd) {
    __shared__ _Float16 At[64 * 72];    // 18 KB
    __shared__ _Float16 Bt[128 * 72];   // 18 KB
    int tid = threadIdx.x;
    int row0 = blockIdx.x * 64;

    const float4* st4 = (const float4*)(state + (size_t)row0 * 64);
    for (int i = tid; i < 1024; i += 256) {
        int r = i >> 4, c4 = (i & 15) << 2;
        float4 v = st4[i];
        union { short4 s; _Float16 h[4]; } u;
        u.h[0] = (_Float16)v.x; u.h[1] = (_Float16)v.y;
        u.h[2] = (_Float16)v.z; u.h[3] = (_Float16)v.w;
        *(short4*)&At[r * 72 + c4] = u.s;
    }
    const short4* wt4 = (const short4*)Wt;
    for (int i = tid; i < 2048; i += 256) {
        int r = i >> 4, c4 = (i & 15) << 2;
        *(short4*)&Bt[r * 72 + c4] = wt4[i];
    }
    __syncthreads();

    int wave = tid >> 6, lane = tid & 63;
    int quad = lane >> 4, m16 = lane & 15;
    int m_loc = wave * 16 + m16;

    f16x8 a0 = *(const f16x8*)&At[m_loc * 72 + quad * 8];
    f16x8 a1 = *(const f16x8*)&At[m_loc * 72 + 32 + quad * 8];

#pragma unroll
    for (int tcol = 0; tcol < 8; tcol++) {
        int n = tcol * 16 + m16;
        f16x8 b0 = *(const f16x8*)&Bt[n * 72 + quad * 8];
        f16x8 b1 = *(const f16x8*)&Bt[n * 72 + 32 + quad * 8];
        f32x4 acc = {0.f, 0.f, 0.f, 0.f};
        acc = __builtin_amdgcn_mfma_f32_16x16x32_f16(a0, b0, acc, 0, 0, 0);
        acc = __builtin_amdgcn_mfma_f32_16x16x32_f16(a1, b1, acc, 0, 0, 0);
#pragma unroll
        for (int r = 0; r < 4; r++) {
            int ml = wave * 16 + quad * 4 + r;
            int m = row0 + ml;
            int node = m >> 3, bb = m & 7;
            size_t base = (size_t)bb * SLICE + (size_t)node * 64;
            if (tcol < 4) {
                HU xu; xu.f = At[ml * 72 + n];
                ushort2 pk;
                pk.x = __half_as_ushort(__float2half_rn(acc[r]));
                pk.y = xu.u;
                *(ushort2*)&G[base + n] = pk;     // low = p_src, high = state(fp16)
            } else {
                Pd[base + (n - 64)] = __float2half_rn(acc[r]);
            }
        }
    }
}

// ---------------- fused segment-softmax + aggregate ----------------
// 4 waves/block; wave w -> node grp*4+w; slice b = blockIdx&7 (XCD-resident slice).
// Within a wave: 4 edge groups x 16 lanes; each lane loads float4 = 4 half2 elements
// (256B contiguous per edge). Butterfly-reduce the 4 groups at the end.
__global__ void __launch_bounds__(256) gat_aggregate(
    const __half2* __restrict__ G,      // slice-major [b][node][64] of {p_src, state}
    const __half* __restrict__ Pds,     // slice-major [b][node][64]
    const int* __restrict__ offsets,
    const int2* __restrict__ edges,
    float4* __restrict__ out4) {
    int bid = blockIdx.x;
    int b = bid & 7;
    int grp = bid >> 3;
    int wave = threadIdx.x >> 6;
    int lane = threadIdx.x & 63;
    int n = (grp << 2) + wave;
    int eidx = lane >> 4;    // edge group 0..3
    int lpart = lane & 15;   // element quad 0..15

    const __half2* Gb = G + (size_t)b * SLICE;
    const __half* Pb = Pds + (size_t)b * SLICE;

    union { float2 f; __half2 h[2]; } pdu;
    pdu.f = *(const float2*)(Pb + n * 64 + lpart * 4);
    float pd[4] = {__low2float(pdu.h[0]), __high2float(pdu.h[0]),
                   __low2float(pdu.h[1]), __high2float(pdu.h[1])};

    int off = offsets[n];
    int cnt = offsets[n + 1] - off;
    const int2* ep = edges + off;
    const float LOG2E = 1.44269504f;

    float l[4] = {0.f, 0.f, 0.f, 0.f};
    float o[4] = {0.f, 0.f, 0.f, 0.f};

    if (cnt > 0) {
        int last = cnt - 1;
        int idx = eidx <= last ? eidx : last;
        int2 rec = ep[idx];
        float4 g = *(const float4*)(Gb + (size_t)rec.x * 64 + lpart * 4);
        float ddl = __int_as_float(rec.y) * LOG2E;
        int j = 0;
        for (;;) {
            int jn = j + 4;
            bool more = jn < cnt;
            int2 rec2; float4 g2; float ddl2;
            if (more) {
                int i2 = jn + eidx; i2 = i2 <= last ? i2 : last;
                rec2 = ep[i2];
                g2 = *(const float4*)(Gb + (size_t)rec2.x * 64 + lpart * 4);
                ddl2 = __int_as_float(rec2.y) * LOG2E;
            }
            bool act = (j + eidx) <= last;
            union { float4 f; __half2 h[4]; } gu; gu.f = g;
#pragma unroll
            for (int i = 0; i < 4; i++) {
                float p = __low2float(gu.h[i]);
                float x = __high2float(gu.h[i]);
                float z = p + pd[i];
                float a = fmaxf(z, 0.2f * z) * ddl;
                float ex = act ? __builtin_amdgcn_exp2f(a) : 0.f;
                l[i] += ex;
                o[i] = fmaf(ex, x, o[i]);
            }
            if (!more) break;
            j = jn; rec = rec2; g = g2; ddl = ddl2;
        }
#pragma unroll
        for (int i = 0; i < 4; i++) {
            l[i] += __shfl_xor(l[i], 16, 64);
            o[i] += __shfl_xor(o[i], 16, 64);
            l[i] += __shfl_xor(l[i], 32, 64);
            o[i] += __shfl_xor(o[i], 32, 64);
        }
    }
    if (eidx == 0) {
        float4 r;
        if (cnt > 0) {
            float r0 = __builtin_amdgcn_rcpf(l[0]);
            float r1 = __builtin_amdgcn_rcpf(l[1]);
            float r2 = __builtin_amdgcn_rcpf(l[2]);
            float r3 = __builtin_amdgcn_rcpf(l[3]);
            r.x = fmaxf(o[0] * r0, 0.f);
            r.y = fmaxf(o[1] * r1, 0.f);
            r.z = fmaxf(o[2] * r2, 0.f);
            r.w = fmaxf(o[3] * r3, 0.f);
        } else {
            r = make_float4(0.f, 0.f, 0.f, 0.f);
        }
        out4[(size_t)n * 128 + b * 16 + lpart] = r;
    }
}

extern "C" void kernel_launch(void* const* d_in, const int* in_sizes, int n_in,
                              void* d_out, int out_size, void* d_ws, size_t ws_size,
                              hipStream_t stream) {
    const float* state  = (const float*)d_in[0];
    // d_in[1] = feature (unused by the math)
    const float* weight = (const float*)d_in[2];
    const int*   src    = (const int*)d_in[3];
    const int*   dst    = (const int*)d_in[4];
    const float* dist   = (const float*)d_in[5];

    // workspace layout (16B-aligned head first)
    __half2*  G      = (__half2*)d_ws;                       // 8*SLICE half2 = 20.48 MB
    __half*   Pd     = (__half*)(G + (size_t)8 * SLICE);     // 8*SLICE half  = 10.24 MB
    _Float16* Wt     = (_Float16*)(Pd + (size_t)8 * SLICE);  // 8192 half = 16 KB
    int2*     edges  = (int2*)(Wt + 8192);                   // E int2 = 1.28 MB
    int*      counts = (int*)(edges + N_EDGES);              // N
    int*      offsets= counts + N_NODES;                     // N+1
    int*      cursor = offsets + N_NODES + 1;                // N

    zero_wt_kernel<<<72, 256, 0, stream>>>(counts, weight, Wt);
    hist_kernel<<<(N_EDGES + 255) / 256, 256, 0, stream>>>(dst, counts);
    scan_kernel<<<1, 1024, 0, stream>>>(counts, offsets, cursor);
    scatter_kernel<<<(N_EDGES + 255) / 256, 256, 0, stream>>>(src, dst, dist, cursor, edges);
    proj_mfma<<<ROWS / 64, 256, 0, stream>>>(state, Wt, G, Pd);
    gat_aggregate<<<N_NODES * 2, 256, 0, stream>>>(G, Pd, offsets, edges, (float4*)d_out);
}